// Round 14
// baseline (34.224 us; speedup 1.0000x reference)
//
#include <hip/hip_runtime.h>

// EctLayer: ect[b,r,t] = sum_{n: batch[n]==b} sigmoid(SCALE*(lin[r] - (x[n]·dir[:,t])))
// N=65536, D=3, T=64, R=64, B=64. SCALE=500.
//
// Round-14: r13 inner loop + minimal per-block front/back-end.
//  - boundary scan: batch=sort(randint(0,64)) => boundary b is within
//    +-768 of b*N/64 (cumulative-binomial sigma=128; window=6sigma). Scan
//    ONLY that window (1536 coalesced loads, single-writer store). A full
//    coalesced sweep FALLBACK runs iff a sentinel survives, so correctness
//    never depends on the statistical assumption.
//  - inner loop (r13): one packed ds_add_u32 (1<<20)|si at bin
//    j1=clamp(r0+1,0,64), si=round(sigmoid*2^9); skip upper-tail r0>=64.
//    count=high 12 bits, si-sum=low 20 (safe: len<2048 -> cnt*2^20<2^31,
//    si-sum<=2047*512<2^20).
//  - epilogue: WAVE 0 ONLY. Two ds_read_b128 per lane cover all 65x4 bins;
//    6-step __shfl_up inclusive scan over lanes (=rows) x4 dirs; one float4
//    coalesced store per lane. Other waves exit after the last barrier.
//  - 1024 blocks = (batch b, t-16th q) x 512 threads; disjoint
//    out[b,:,q*4..+4) slices; no global atomics, no memset, no pre/post
//    kernels. 3 hot-path syncs.
//  - errors: quant ~0.06, dropped tails <= ~0.2; threshold 19.44.

#define T_DIRS   64
#define R_STEPS  64
#define NROWS    65                     // bins 0..64
#define N_BATCH  64
#define TSPLIT   16
#define TQW      4                      // dirs per block
#define PSW      16                     // point slots per wave
#define THREADS  512
#define NWAVES   8
#define WIN      768                    // boundary search half-window

#define RADIUS_F 1.1f
#define STEP_F   (2.0f * RADIUS_F / (R_STEPS - 1))          // 0.0349206
#define INV_STEP (1.0f / STEP_F)
#define OFF_F    (RADIUS_F * INV_STEP)                      // 31.5
#define MEXP     (-500.0f * STEP_F * 1.4426950408889634f)   // -K*log2(e)
#define FIXP     512.0f
#define INV_FIXP (1.0f / 512.0f)
#define CNT_ONE  (1u << 20)
#define SI_MASK  0xFFFFFu

__global__ __launch_bounds__(THREADS) void ect_kernel(
    const float* __restrict__ x,      // [N,3]
    const float* __restrict__ dirs,   // [3,T]
    const int*   __restrict__ batch,  // [N] sorted
    float* __restrict__ out,          // [B,R,T]
    int N)
{
    __shared__ unsigned s_a[NROWS * TQW];       // 1040 B packed bins
    __shared__ int      s_lo, s_hi;

    const int tid  = threadIdx.x;
    const int b    = blockIdx.x >> 4;
    const int q    = blockIdx.x & (TSPLIT - 1);
    const int lane = tid & 63;
    const int w    = tid >> 6;
    const int ps   = lane >> 2;                 // point slot 0..15
    const int tq   = lane & (TQW - 1);          // local dir 0..3
    const int tg   = q * TQW + tq;              // global dir

    for (int i = tid; i < NROWS * TQW; i += THREADS) s_a[i] = 0u;
    if (tid == 0) { s_lo = -1; s_hi = -1; }

    const float d0 = dirs[tg];
    const float d1 = dirs[T_DIRS + tg];
    const float d2 = dirs[2 * T_DIRS + tg];
    __syncthreads();

    // windowed boundary scan (coalesced, single-writer)
    {
        const int seg = N >> 6;                 // expected segment length
        int c0 = b * seg;                       // expected lo boundary
        int a0 = max(0, c0 - WIN), a1 = min(N, c0 + WIN);
        for (int j = a0 + tid; j < a1; j += THREADS) {
            int v  = batch[j];
            int vp = (j == 0) ? -1 : batch[j - 1];
            if (v >= b && vp < b) s_lo = j;
        }
        int c1 = (b + 1) * seg;                 // expected hi boundary
        int b0 = max(0, c1 - WIN), b1 = min(N, c1 + WIN);
        for (int j = b0 + tid; j < b1; j += THREADS) {
            int v  = batch[j];
            int vp = (j == 0) ? -1 : batch[j - 1];
            if (v > b && vp <= b) s_hi = j;
        }
    }
    __syncthreads();

    // fallback: full coalesced sweep iff a sentinel survived (~never taken)
    if (s_lo < 0 || s_hi < 0) {
        for (int j = tid; j < N; j += THREADS) {
            int v  = batch[j];
            int vp = (j == 0) ? -1 : batch[j - 1];
            if (v >= b && vp < b)  s_lo = j;
            if (v >  b && vp <= b) s_hi = j;
        }
        __syncthreads();
    }
    const int lo  = (s_lo < 0) ? N : s_lo;      // lo<0: no point >= b
    const int hi  = (s_hi < 0) ? N : s_hi;      // hi<0: batch ends inside b
    const int len = hi - lo;
    const float* xb = x + (size_t)lo * 3;

    // inner loop: direct global x reads (L2-resident, 4-lane-uniform addr)
    for (int p = w * PSW + ps; p < len; p += NWAVES * PSW) {
        float x0 = xb[p * 3 + 0];
        float x1 = xb[p * 3 + 1];
        float x2 = xb[p * 3 + 2];
        float nh  = fmaf(x2, d2, fmaf(x1, d1, x0 * d0));
        float u   = fmaf(nh, INV_STEP, OFF_F);
        float r0f = rintf(u);
        float dd  = r0f - u;                               // [-0.5, 0.5]
        float e   = __builtin_amdgcn_exp2f(dd * MEXP);
        float s   = __builtin_amdgcn_rcpf(1.0f + e);       // sigmoid at r0
        unsigned si = (unsigned)fmaf(s, FIXP, 0.5f);       // [0, 2^9]
        int j1 = (int)r0f + 1;
        if (j1 <= R_STEPS) {                    // skip upper-tail trash
            j1 = max(j1, 0);
            atomicAdd(&s_a[j1 * TQW + tq], CNT_ONE | si);  // one ds_add_u32
        }
    }
    __syncthreads();
    if (w != 0) return;                         // single-wave epilogue

    // lane r (0..63) handles output row r for all 4 local dirs.
    // row r:   counts (>>20) feed the inclusive lane-scan;
    // row r+1: si low bits give the transition term.
    uint4 rowv = *(const uint4*)&s_a[lane * TQW];          // ds_read_b128
    uint4 r64  = *(const uint4*)&s_a[R_STEPS * TQW];       // row 64 broadcast

    unsigned c0 = rowv.x >> 20, c1 = rowv.y >> 20,
             c2 = rowv.z >> 20, c3 = rowv.w >> 20;
    unsigned s0 = rowv.x & SI_MASK, s1 = rowv.y & SI_MASK,
             s2 = rowv.z & SI_MASK, s3 = rowv.w & SI_MASK;

    // si of row lane+1 (lane 63 takes row 64 directly)
    unsigned n0 = __shfl_down(s0, 1, 64), n1 = __shfl_down(s1, 1, 64),
             n2 = __shfl_down(s2, 1, 64), n3 = __shfl_down(s3, 1, 64);
    if (lane == 63) {
        n0 = r64.x & SI_MASK; n1 = r64.y & SI_MASK;
        n2 = r64.z & SI_MASK; n3 = r64.w & SI_MASK;
    }

    // 6-step inclusive scan over lanes (rows 0..63)
#pragma unroll
    for (int d = 1; d < 64; d <<= 1) {
        unsigned u0 = __shfl_up(c0, d, 64), u1 = __shfl_up(c1, d, 64),
                 u2 = __shfl_up(c2, d, 64), u3 = __shfl_up(c3, d, 64);
        if (lane >= d) { c0 += u0; c1 += u1; c2 += u2; c3 += u3; }
    }

    float4 o;
    o.x = (float)c0 + (float)n0 * INV_FIXP;
    o.y = (float)c1 + (float)n1 * INV_FIXP;
    o.z = (float)c2 + (float)n2 * INV_FIXP;
    o.w = (float)c3 + (float)n3 * INV_FIXP;
    *(float4*)&out[((size_t)b << 12) | (lane << 6) | (q * TQW)] = o;
}

extern "C" void kernel_launch(void* const* d_in, const int* in_sizes, int n_in,
                              void* d_out, int out_size, void* d_ws, size_t ws_size,
                              hipStream_t stream) {
    const float* x     = (const float*)d_in[0];
    const float* dirs  = (const float*)d_in[1];
    const int*   batch = (const int*)d_in[3];
    float* out = (float*)d_out;
    const int N = in_sizes[3];

    ect_kernel<<<dim3(N_BATCH * TSPLIT), dim3(THREADS), 0, stream>>>(
        x, dirs, batch, out, N);
}

// Round 15
// 12.125 us; speedup vs baseline: 2.8227x; 2.8227x over previous
//
#include <hip/hip_runtime.h>

// EctLayer: ect[b,r,t] = sum_{n: batch[n]==b} sigmoid(SCALE*(lin[r] - (x[n]·dir[:,t])))
// N=65536, D=3, T=64, R=64, B=64. SCALE=500.
//
// Round-15: r14 + analytic boundary closure (fixes the b=63 straggler that
// made r14's "fallback iff sentinel survives" deterministically true: no
// element is > 63, so all 16 b=63 blocks full-swept 65536 elems every call).
//  - lo(0)=0 and hi(63)=N are GUARANTEED (batch values in [0,64)), so those
//    scans are skipped; other boundaries use the +-768 window (6 sigma of
//    cumulative binomial). Full-sweep fallback remains, now probabilistic
//    only (~1e-9/boundary).
//  - inner loop (r13): one packed ds_add_u32 (1<<20)|si at bin
//    j1=clamp(r0+1,0,64), si=round(sigmoid*2^9); skip upper-tail r0>=64.
//    count=high 12 bits, si-sum=low 20 (len<2048 -> no overflow).
//  - epilogue: wave 0 only; uint4 LDS row read, 6-step __shfl_up inclusive
//    scan (4 dirs in parallel), one float4 store per lane.
//  - 1024 blocks = (batch b, t-16th q) x 512 threads; disjoint
//    out[b,:,q*4..+4) slices; no global atomics, no memset, no pre/post
//    kernels; 3 hot-path syncs.
//  - errors: quant ~0.06, dropped tails <= ~0.2; threshold 19.44.

#define T_DIRS   64
#define R_STEPS  64
#define NROWS    65                     // bins 0..64
#define N_BATCH  64
#define TSPLIT   16
#define TQW      4                      // dirs per block
#define PSW      16                     // point slots per wave
#define THREADS  512
#define NWAVES   8
#define WIN      768                    // boundary search half-window

#define RADIUS_F 1.1f
#define STEP_F   (2.0f * RADIUS_F / (R_STEPS - 1))          // 0.0349206
#define INV_STEP (1.0f / STEP_F)
#define OFF_F    (RADIUS_F * INV_STEP)                      // 31.5
#define MEXP     (-500.0f * STEP_F * 1.4426950408889634f)   // -K*log2(e)
#define FIXP     512.0f
#define INV_FIXP (1.0f / 512.0f)
#define CNT_ONE  (1u << 20)
#define SI_MASK  0xFFFFFu

__global__ __launch_bounds__(THREADS) void ect_kernel(
    const float* __restrict__ x,      // [N,3]
    const float* __restrict__ dirs,   // [3,T]
    const int*   __restrict__ batch,  // [N] sorted, values in [0,64)
    float* __restrict__ out,          // [B,R,T]
    int N)
{
    __shared__ unsigned s_a[NROWS * TQW];       // 1040 B packed bins
    __shared__ int      s_lo, s_hi;

    const int tid  = threadIdx.x;
    const int b    = blockIdx.x >> 4;
    const int q    = blockIdx.x & (TSPLIT - 1);
    const int lane = tid & 63;
    const int w    = tid >> 6;
    const int ps   = lane >> 2;                 // point slot 0..15
    const int tq   = lane & (TQW - 1);          // local dir 0..3
    const int tg   = q * TQW + tq;              // global dir

    for (int i = tid; i < NROWS * TQW; i += THREADS) s_a[i] = 0u;
    if (tid == 0) {
        s_lo = (b == 0) ? 0 : -1;               // analytic: batch[j] >= 0
        s_hi = (b == N_BATCH - 1) ? N : -1;     // analytic: batch[j] <= 63
    }

    const float d0 = dirs[tg];
    const float d1 = dirs[T_DIRS + tg];
    const float d2 = dirs[2 * T_DIRS + tg];
    __syncthreads();

    // windowed boundary scan (coalesced, single-writer); skipped when analytic
    {
        const int seg = N >> 6;                 // expected segment length
        if (b != 0) {
            int c0 = b * seg;
            int a0 = max(0, c0 - WIN), a1 = min(N, c0 + WIN);
            for (int j = a0 + tid; j < a1; j += THREADS) {
                int v  = batch[j];
                int vp = (j == 0) ? -1 : batch[j - 1];
                if (v >= b && vp < b) s_lo = j;
            }
        }
        if (b != N_BATCH - 1) {
            int c1 = (b + 1) * seg;
            int b0 = max(0, c1 - WIN), b1 = min(N, c1 + WIN);
            for (int j = b0 + tid; j < b1; j += THREADS) {
                int v  = batch[j];
                int vp = (j == 0) ? -1 : batch[j - 1];
                if (v > b && vp <= b) s_hi = j;
            }
        }
    }
    __syncthreads();

    // fallback: full coalesced sweep iff a sentinel survived (prob ~1e-9)
    if (s_lo < 0 || s_hi < 0) {
        for (int j = tid; j < N; j += THREADS) {
            int v  = batch[j];
            int vp = (j == 0) ? -1 : batch[j - 1];
            if (v >= b && vp < b)  s_lo = j;
            if (v >  b && vp <= b) s_hi = j;
        }
        __syncthreads();
    }
    const int lo  = (s_lo < 0) ? N : s_lo;      // still -1: segment empty
    const int hi  = (s_hi < 0) ? N : s_hi;      // still -1: tail reaches N
    const int len = hi - lo;
    const float* xb = x + (size_t)lo * 3;

    // inner loop: direct global x reads (L2-resident, 4-lane-uniform addr)
    for (int p = w * PSW + ps; p < len; p += NWAVES * PSW) {
        float x0 = xb[p * 3 + 0];
        float x1 = xb[p * 3 + 1];
        float x2 = xb[p * 3 + 2];
        float nh  = fmaf(x2, d2, fmaf(x1, d1, x0 * d0));
        float u   = fmaf(nh, INV_STEP, OFF_F);
        float r0f = rintf(u);
        float dd  = r0f - u;                               // [-0.5, 0.5]
        float e   = __builtin_amdgcn_exp2f(dd * MEXP);
        float s   = __builtin_amdgcn_rcpf(1.0f + e);       // sigmoid at r0
        unsigned si = (unsigned)fmaf(s, FIXP, 0.5f);       // [0, 2^9]
        int j1 = (int)r0f + 1;
        if (j1 <= R_STEPS) {                    // skip upper-tail trash
            j1 = max(j1, 0);
            atomicAdd(&s_a[j1 * TQW + tq], CNT_ONE | si);  // one ds_add_u32
        }
    }
    __syncthreads();
    if (w != 0) return;                         // single-wave epilogue

    // lane r handles output row r for the block's 4 dirs.
    uint4 rowv = *(const uint4*)&s_a[lane * TQW];          // ds_read_b128
    uint4 r64  = *(const uint4*)&s_a[R_STEPS * TQW];       // row 64 broadcast

    unsigned c0 = rowv.x >> 20, c1 = rowv.y >> 20,
             c2 = rowv.z >> 20, c3 = rowv.w >> 20;
    unsigned s0 = rowv.x & SI_MASK, s1 = rowv.y & SI_MASK,
             s2 = rowv.z & SI_MASK, s3 = rowv.w & SI_MASK;

    // si of row lane+1 (lane 63 takes row 64 directly)
    unsigned n0 = __shfl_down(s0, 1, 64), n1 = __shfl_down(s1, 1, 64),
             n2 = __shfl_down(s2, 1, 64), n3 = __shfl_down(s3, 1, 64);
    if (lane == 63) {
        n0 = r64.x & SI_MASK; n1 = r64.y & SI_MASK;
        n2 = r64.z & SI_MASK; n3 = r64.w & SI_MASK;
    }

    // 6-step inclusive scan over lanes (rows 0..63)
#pragma unroll
    for (int d = 1; d < 64; d <<= 1) {
        unsigned u0 = __shfl_up(c0, d, 64), u1 = __shfl_up(c1, d, 64),
                 u2 = __shfl_up(c2, d, 64), u3 = __shfl_up(c3, d, 64);
        if (lane >= d) { c0 += u0; c1 += u1; c2 += u2; c3 += u3; }
    }

    float4 o;
    o.x = (float)c0 + (float)n0 * INV_FIXP;
    o.y = (float)c1 + (float)n1 * INV_FIXP;
    o.z = (float)c2 + (float)n2 * INV_FIXP;
    o.w = (float)c3 + (float)n3 * INV_FIXP;
    *(float4*)&out[((size_t)b << 12) | (lane << 6) | (q * TQW)] = o;
}

extern "C" void kernel_launch(void* const* d_in, const int* in_sizes, int n_in,
                              void* d_out, int out_size, void* d_ws, size_t ws_size,
                              hipStream_t stream) {
    const float* x     = (const float*)d_in[0];
    const float* dirs  = (const float*)d_in[1];
    const int*   batch = (const int*)d_in[3];
    float* out = (float*)d_out;
    const int N = in_sizes[3];

    ect_kernel<<<dim3(N_BATCH * TSPLIT), dim3(THREADS), 0, stream>>>(
        x, dirs, batch, out, N);
}